// Round 4
// baseline (124.160 us; speedup 1.0000x reference)
//
#include <hip/hip_runtime.h>

typedef unsigned int u32;
typedef unsigned short u16;

#define Cn 128
#define ICn 64
#define Nn 4096
#define Mn 1024

typedef __attribute__((ext_vector_type(8))) short s8v;   // 8 bf16 (4 VGPRs)
typedef __attribute__((ext_vector_type(4))) float f4v;   // 4 fp32 acc

__device__ __forceinline__ float bf2f(u16 u){ union{u32 i; float f;} v; v.i = ((u32)u) << 16; return v.f; }
__device__ __forceinline__ u16 f2bf(float f){ union{float f; u32 i;} v; v.f = f; u32 r = v.i + 0x7fffu + ((v.i >> 16) & 1u); return (u16)(r >> 16); }
__device__ __forceinline__ u32 pk2(float lo, float hi){ return (u32)f2bf(lo) | ((u32)f2bf(hi) << 16); }

// ---------------------------------------------------------------------------
// K1 (MFMA, weight-prep folded in): per (row-pair r, half-width wb, batch b).
// K-SPLIT weight staging: conv K=128 done in two halves; w-tile region is
// 18.4 KB (vs 34.8) -> total LDS ~47.4 KB -> 3 blocks/CU (was 2 @ 64 KB).
// LDS char smem[47368]:
//   xsT @0      u16 [64 lp][136 c]  17408 B (swizzled cols, full K)
//   wt  @17408  u16 2x[64 ic][72]   18432 B (phase A halves; phase B: w2t[128][72])
//   ph  @35840  f32 [32][68]         8704 B
//   xgr @44544  u16 [16][72]         2304 B
//   u3s @46848  f32 [129]             520 B
// ---------------------------------------------------------------------------
__global__ __launch_bounds__(256, 3) void k_conv(
    const float* __restrict__ x,
    const float* __restrict__ w1, const float* __restrict__ b1,
    const float* __restrict__ w3, const float* __restrict__ b3,
    const float* __restrict__ w4, const float* __restrict__ b4,
    const float* __restrict__ w5, const float* __restrict__ w2,
    float* __restrict__ t_o, float* __restrict__ p_o, float* __restrict__ g_o)
{
    const int tile = blockIdx.x;   // 0..63
    const int r  = tile >> 1;      // row-pair 0..31
    const int wb = tile & 1;       // half-width 0..1
    const int b  = blockIdx.y;
    const int tid = threadIdx.x;

    __shared__ __align__(16) char smem[47368];
    u16* xsT = (u16*)smem;                 // [64][136]
    u16* wt1 = (u16*)(smem + 17408);       // [64][72] (half)
    u16* wt4 = (u16*)(smem + 26624);       // [64][72] (half)
    u16* w2t = (u16*)(smem + 17408);       // phase B [128][72]
    float* ph = (float*)(smem + 35840);    // [32][68]
    u16* xgr = (u16*)(smem + 44544);       // [16][72]
    float* u3s = (float*)(smem + 46848);   // [129]

    // ---- stage x^T as bf16 channel-pairs, swizzled ----
    #pragma unroll
    for (int it = 0; it < 4; ++it) {
        int f = tid + 256 * it;        // 1024 tasks: cp = f>>4, rem = f&15
        int cp = f >> 4, rem = f & 15;
        int rl = rem >> 3, wq = rem & 7;
        const float* src = x + ((size_t)(b * Cn + 2 * cp)) * Nn + (2 * r + rl) * 64 + 32 * wb + 4 * wq;
        float4 v0 = *(const float4*)src;
        float4 v1 = *(const float4*)(src + Nn);
        int lp0 = rl * 32 + 4 * wq;
        int cS = (2 * cp) ^ (wq << 3); // ((lp0+k)>>2)&7 == wq for k=0..3
        *(u32*)&xsT[(lp0 + 0) * 136 + cS] = pk2(v0.x, v1.x);
        *(u32*)&xsT[(lp0 + 1) * 136 + cS] = pk2(v0.y, v1.y);
        *(u32*)&xsT[(lp0 + 2) * 136 + cS] = pk2(v0.z, v1.z);
        *(u32*)&xsT[(lp0 + 3) * 136 + cS] = pk2(v0.w, v1.w);
    }
    // ---- stage W1, W4 half kh=0 (c in [0,64)) ----
    #pragma unroll
    for (int it = 0; it < 2; ++it) {
        int f = tid + 256 * it;        // 512 tasks: ic = f>>3, cq = f&7
        int ic = f >> 3, cq = f & 7;
        const float* s1 = &w1[ic * Cn + 8 * cq];
        const float* s4 = &w4[ic * Cn + 8 * cq];
        float4 a0 = *(const float4*)s1, a1v = *(const float4*)(s1 + 4);
        float4 d0 = *(const float4*)s4, d1v = *(const float4*)(s4 + 4);
        uint4 A, D;
        A.x = pk2(a0.x, a0.y); A.y = pk2(a0.z, a0.w); A.z = pk2(a1v.x, a1v.y); A.w = pk2(a1v.z, a1v.w);
        D.x = pk2(d0.x, d0.y); D.y = pk2(d0.z, d0.w); D.z = pk2(d1v.x, d1v.y); D.w = pk2(d1v.z, d1v.w);
        *(uint4*)&wt1[ic * 72 + 8 * cq] = A;
        *(uint4*)&wt4[ic * 72 + 8 * cq] = D;
    }
    // ---- u3 = w5[:64].W3 (redundant, L2-resident) ----
    if (tid < 128) {
        float s0 = 0.f, s1 = 0.f;
        #pragma unroll 8
        for (int ic = 0; ic < 64; ic += 2) {
            s0 += w5[ic]     * w3[ic * Cn + tid];
            s1 += w5[ic + 1] * w3[(ic + 1) * Cn + tid];
        }
        u3s[tid] = s0 + s1;
    } else if (tid == 128) {
        float s = 0.f;
        #pragma unroll 16
        for (int ic = 0; ic < 64; ++ic) s += w5[ic] * b3[ic];
        u3s[128] = s;
    }
    __syncthreads();

    const int lane = tid & 63;
    const int wv   = tid >> 6;         // wave 0..3 -> lp block [16wv,16wv+16)
    const int col  = lane & 15;
    const int quad = lane >> 4;

    // ---- dual conv MFMA, K-split: D[ic][lp] ----
    f4v acc1[4] = {}, acc4[4] = {};
    const u16* xrow = &xsT[(16 * wv + col) * 136];
    const int xsw = (((16 * wv + col) >> 2) & 7) << 3;

    #pragma unroll
    for (int kh = 0; kh < 2; ++kh) {
        if (kh == 1) {
            __syncthreads();   // wt reads of half0 done
            #pragma unroll
            for (int it = 0; it < 2; ++it) {
                int f = tid + 256 * it;
                int ic = f >> 3, cq = f & 7;
                const float* s1 = &w1[ic * Cn + 64 + 8 * cq];
                const float* s4 = &w4[ic * Cn + 64 + 8 * cq];
                float4 a0 = *(const float4*)s1, a1v = *(const float4*)(s1 + 4);
                float4 d0 = *(const float4*)s4, d1v = *(const float4*)(s4 + 4);
                uint4 A, D;
                A.x = pk2(a0.x, a0.y); A.y = pk2(a0.z, a0.w); A.z = pk2(a1v.x, a1v.y); A.w = pk2(a1v.z, a1v.w);
                D.x = pk2(d0.x, d0.y); D.y = pk2(d0.z, d0.w); D.z = pk2(d1v.x, d1v.y); D.w = pk2(d1v.z, d1v.w);
                *(uint4*)&wt1[ic * 72 + 8 * cq] = A;
                *(uint4*)&wt4[ic * 72 + 8 * cq] = D;
            }
            __syncthreads();   // half1 staged
        }
        #pragma unroll
        for (int kb2 = 0; kb2 < 2; ++kb2) {
            int kb = 2 * kh + kb2;
            s8v bx = *(const s8v*)&xrow[(kb * 32 + quad * 8) ^ xsw];
            #pragma unroll
            for (int icb = 0; icb < 4; ++icb) {
                s8v a1 = *(const s8v*)&wt1[(icb * 16 + col) * 72 + kb2 * 32 + quad * 8];
                s8v a4 = *(const s8v*)&wt4[(icb * 16 + col) * 72 + kb2 * 32 + quad * 8];
                acc1[icb] = __builtin_amdgcn_mfma_f32_16x16x32_bf16(a1, bx, acc1[icb], 0, 0, 0);
                acc4[icb] = __builtin_amdgcn_mfma_f32_16x16x32_bf16(a4, bx, acc4[icb], 0, 0, 0);
            }
        }
    }
    __syncthreads();   // conv MFMA LDS reads done; wt region dead

    // ---- a1: horizontal pair max in-register, write half-pool to ph ----
    const int lp = 16 * wv + col;
    const int rl = lp >> 5, wl = lp & 31, pw = wl >> 1;
    const bool wr = (wl & 1) == 0;
    #pragma unroll
    for (int icb = 0; icb < 4; ++icb)
        #pragma unroll
        for (int reg = 0; reg < 4; ++reg) {
            float v = acc1[icb][reg];
            float vm = fmaxf(v, __shfl_xor(v, 1, 64));
            if (wr) ph[(rl * 16 + pw) * 68 + icb * 16 + quad * 4 + reg] = vm;
        }
    __syncthreads();

    // ---- xgr = vertical pool + bias (bf16) ----
    #pragma unroll
    for (int it = 0; it < 4; ++it) {
        int e = tid + 256 * it;        // 1024: pw = e>>6, ic = e&63
        int pwq = e >> 6, ic = e & 63;
        float v = fmaxf(ph[pwq * 68 + ic], ph[(16 + pwq) * 68 + ic]) + b1[ic];
        xgr[pwq * 72 + ic] = f2bf(v);
    }
    // ---- t = u3.x + c3, all 256 threads (4 lanes per pixel) ----
    {
        int px = tid >> 2, part = tid & 3;
        const int tsw = ((px >> 2) & 7) << 3;
        const u16* xr = &xsT[px * 136];
        float s = 0.f;
        #pragma unroll
        for (int cq = 0; cq < 4; ++cq) {
            int u = part * 32 + cq * 8;
            s8v xv = *(const s8v*)&xr[u ^ tsw];
            #pragma unroll
            for (int j = 0; j < 8; ++j) s += u3s[u + j] * bf2f((u16)xv[j]);
        }
        s += __shfl_xor(s, 1, 64);
        s += __shfl_xor(s, 2, 64);
        if (part == 0)
            t_o[(size_t)b * Nn + (2 * r + (px >> 5)) * 64 + 32 * wb + (px & 31)] = s + u3s[128];
    }
    __syncthreads();   // xgr ready; ph consumed

    // ---- stage W2 (f32->bf16) [co][72]; a4 half-pool -> ph ----
    #pragma unroll
    for (int it = 0; it < 4; ++it) {
        int f = tid + 256 * it;        // 1024 groups: co = f>>3, iq = f&7
        int co = f >> 3, iq = f & 7;
        const float4* s2 = (const float4*)&w2[f * 8];
        float4 a0 = s2[0], a1v = s2[1];
        uint4 V;
        V.x = pk2(a0.x, a0.y); V.y = pk2(a0.z, a0.w); V.z = pk2(a1v.x, a1v.y); V.w = pk2(a1v.z, a1v.w);
        *(uint4*)&w2t[co * 72 + 8 * iq] = V;
    }
    #pragma unroll
    for (int icb = 0; icb < 4; ++icb)
        #pragma unroll
        for (int reg = 0; reg < 4; ++reg) {
            float v = acc4[icb][reg];
            float vm = fmaxf(v, __shfl_xor(v, 1, 64));
            if (wr) ph[(rl * 16 + pw) * 68 + icb * 16 + quad * 4 + reg] = vm;
        }
    __syncthreads();

    // ---- g = xgr . W2^T via MFMA: wave wv -> co blocks {2wv, 2wv+1} ----
    #pragma unroll
    for (int cob2 = 0; cob2 < 2; ++cob2) {
        int cob = 2 * wv + cob2;
        f4v gacc = {};
        #pragma unroll
        for (int kb = 0; kb < 2; ++kb) {
            s8v a  = *(const s8v*)&xgr[col * 72 + kb * 32 + quad * 8];
            s8v bb = *(const s8v*)&w2t[(cob * 16 + col) * 72 + kb * 32 + quad * 8];
            gacc = __builtin_amdgcn_mfma_f32_16x16x32_bf16(a, bb, gacc, 0, 0, 0);
        }
        #pragma unroll
        for (int reg = 0; reg < 4; ++reg) {
            int pwr = quad * 4 + reg;
            int m = r * 32 + wb * 16 + pwr;
            g_o[((size_t)b * Mn + m) * 128 + cob * 16 + col] = gacc[reg];
        }
    }

    // ---- p from a4 pool ----
    if (tid < 16) {
        float s = 0.f;
        #pragma unroll 8
        for (int ic = 0; ic < 64; ++ic) {
            float pv = fmaxf(ph[tid * 68 + ic], ph[(16 + tid) * 68 + ic]) + b4[ic];
            s += w5[64 + ic] * pv;
        }
        p_o[(size_t)b * Mn + r * 32 + wb * 16 + tid] = s;
    }
}

// ---------------------------------------------------------------------------
// K3: rank-by-counting, 512 threads: 16 lanes per key, 32 keys per block.
// ---------------------------------------------------------------------------
__global__ __launch_bounds__(512) void k_rank(
    const float* __restrict__ p, float* __restrict__ ps, int* __restrict__ perm)
{
    const int seg = blockIdx.x;    // 0..31
    const int b   = blockIdx.y;
    const int tid = threadIdx.x;
    __shared__ float pls[1024];
    #pragma unroll
    for (int it = 0; it < 2; ++it) pls[tid + 512 * it] = p[b * 1024 + tid + 512 * it];
    __syncthreads();
    const int m = seg * 32 + (tid >> 4);
    const int sub = tid & 15;
    const float key = pls[m];
    int rank = 0;
    #pragma unroll 8
    for (int jj = 0; jj < 64; ++jj) {
        int j = sub + jj * 16;
        float v = pls[j];
        rank += (v < key || (v == key && j < m)) ? 1 : 0;
    }
    rank += __shfl_xor(rank, 1, 64);
    rank += __shfl_xor(rank, 2, 64);
    rank += __shfl_xor(rank, 4, 64);
    rank += __shfl_xor(rank, 8, 64);
    if (sub == 0) {
        ps[b * 1024 + rank]   = key;
        perm[b * 1024 + rank] = m;
    }
}

// ---------------------------------------------------------------------------
// K4: per 32-j segment chunk sums -> csab[seg][co] = {sum g, sum p*g} (float2)
// ---------------------------------------------------------------------------
__global__ __launch_bounds__(512) void k_scanA(
    const float* __restrict__ g, const float* __restrict__ ps, const int* __restrict__ perm,
    float2* __restrict__ csab)
{
    const int seg = blockIdx.x;
    const int b = blockIdx.y;
    const int tid = threadIdx.x;
    const int co = tid & 127, jh = tid >> 7;   // jh 0..3
    __shared__ float redA[4][128], redB[4][128];
    __shared__ float pl[32];
    __shared__ int   pml[32];
    if (tid < 32) { pl[tid] = ps[b * 1024 + seg * 32 + tid]; pml[tid] = perm[b * 1024 + seg * 32 + tid]; }
    __syncthreads();
    float sA = 0.f, sB = 0.f;
    #pragma unroll
    for (int jj = jh * 8; jj < jh * 8 + 8; ++jj) {
        float gv = g[((size_t)b * Mn + pml[jj]) * 128 + co];
        sA += gv; sB += pl[jj] * gv;
    }
    redA[jh][co] = sA; redB[jh][co] = sB;
    __syncthreads();
    if (tid < 128) {
        float2 v;
        v.x = (redA[0][tid] + redA[1][tid]) + (redA[2][tid] + redA[3][tid]);
        v.y = (redB[0][tid] + redB[1][tid]) + (redB[2][tid] + redB[3][tid]);
        csab[(b * 32 + seg) * 128 + tid] = v;
    }
}

// ---------------------------------------------------------------------------
// K5: suffix-sum walk -> SAB[b][k][co] (float2). 4 threads per co: local
// partials + offset step in LDS -> serial walk depth 8 (was 32).
// ---------------------------------------------------------------------------
__global__ __launch_bounds__(512) void k_scanC(
    const float* __restrict__ g, const float* __restrict__ ps, const int* __restrict__ perm,
    const float2* __restrict__ csab, float2* __restrict__ SAB)
{
    const int seg = blockIdx.x;
    const int b = blockIdx.y;
    const int tid = threadIdx.x;
    __shared__ float gs[32 * 128];
    __shared__ float pl[32];
    __shared__ int   pml[32];
    __shared__ float redA[4][128], redB[4][128];
    if (tid < 32) { pl[tid] = ps[b * 1024 + seg * 32 + tid]; pml[tid] = perm[b * 1024 + seg * 32 + tid]; }
    __syncthreads();
    #pragma unroll
    for (int it = 0; it < 8; ++it) {
        int f = tid + 512 * it;
        int jj = f >> 7, co = f & 127;
        gs[jj * 128 + co] = g[((size_t)b * Mn + pml[jj]) * 128 + co];
    }
    __syncthreads();

    const int q = tid >> 7;          // 0..3: jj range [8q, 8q+8)
    const int co = tid & 127;

    // local partials over this thread's 8 rows
    float sA = 0.f, sB = 0.f;
    #pragma unroll
    for (int jj = 8 * q; jj < 8 * q + 8; ++jj) {
        float gv = gs[jj * 128 + co];
        sA += gv; sB += pl[jj] * gv;
    }
    redA[q][co] = sA; redB[q][co] = sB;

    // global base: suffix of csab over segments > seg (redundant per q)
    float rA = 0.f, rB = 0.f;
    #pragma unroll 4
    for (int s2 = seg + 1; s2 < 32; ++s2) {
        float2 v = csab[(b * 32 + s2) * 128 + co];
        rA += v.x; rB += v.y;
    }
    __syncthreads();
    #pragma unroll
    for (int q2 = q + 1; q2 < 4; ++q2) { rA += redA[q2][co]; rB += redB[q2][co]; }

    if (seg == 31 && tid < 128) SAB[((size_t)b * 1025 + 1024) * 128 + co] = make_float2(0.f, 0.f);
    #pragma unroll
    for (int jj = 8 * q + 7; jj >= 8 * q; --jj) {
        float gv = gs[jj * 128 + co];
        rA += gv;
        rB += pl[jj] * gv;
        SAB[((size_t)b * 1025 + seg * 32 + jj) * 128 + co] = make_float2(rA, rB);
    }
}

// ---------------------------------------------------------------------------
// K6: out = ((t[n]*SA[k(n)][co] + SB[k(n)][co])/M)*sc[co] + bs[co] + x
// 512 threads; SA/SB prefetched per-sub into registers (overlap with compute).
// ---------------------------------------------------------------------------
__global__ __launch_bounds__(512) void k_final(
    const float* __restrict__ x, const float* __restrict__ t,
    const float* __restrict__ ps, const float2* __restrict__ SAB,
    const float* __restrict__ b2, const float* __restrict__ gamma, const float* __restrict__ beta,
    const float* __restrict__ mean, const float* __restrict__ var,
    float* __restrict__ out)
{
    const int nt = blockIdx.x;
    const int b = blockIdx.y;
    const int tid = threadIdx.x;
    const int n0 = nt * 128;
    __shared__ float psl[1024];
    __shared__ float tl[128];
    __shared__ int   kl[128];
    __shared__ float sc[128], bs[128];
    __shared__ float sa_s[32][129], sb_s[32][129];

    #pragma unroll
    for (int it = 0; it < 2; ++it) psl[tid + 512 * it] = ps[b * 1024 + tid + 512 * it];
    __syncthreads();
    if (tid < 128) {
        float tv = t[(size_t)b * Nn + n0 + tid];
        tl[tid] = tv;
        float key = -tv;
        int lo = 0, hi = 1024;
        while (lo < hi) { int mid = (lo + hi) >> 1; if (psl[mid] > key) hi = mid; else lo = mid + 1; }
        kl[tid] = lo;
    } else if (tid < 256) {
        int co = tid - 128;
        float s = gamma[co] * rsqrtf(var[co] + 1e-5f);
        sc[co] = s * (1.0f / 1024.0f);             // fold 1/M into BN scale
        bs[co] = (b2[co] - mean[co]) * s + beta[co];
    }
    __syncthreads();

    // prefetch pipeline: 8 float2 rows per thread per sub
    float2 pf[8], pf2[8];
    {
        #pragma unroll
        for (int i2 = 0; i2 < 8; ++i2) {
            int f = tid + 512 * i2;
            int rowl = f >> 7, co = f & 127;
            pf[i2] = SAB[((size_t)b * 1025 + kl[rowl]) * 128 + co];
        }
    }
    for (int sub = 0; sub < 4; ++sub) {
        #pragma unroll
        for (int i2 = 0; i2 < 8; ++i2) {
            int f = tid + 512 * i2;
            int rowl = f >> 7, co = f & 127;
            sa_s[rowl][co] = pf[i2].x;
            sb_s[rowl][co] = pf[i2].y;
        }
        if (sub < 3) {
            #pragma unroll
            for (int i2 = 0; i2 < 8; ++i2) {
                int f = tid + 512 * i2;
                int rowl = f >> 7, co = f & 127;
                pf2[i2] = SAB[((size_t)b * 1025 + kl[(sub + 1) * 32 + rowl]) * 128 + co];
            }
        }
        __syncthreads();
        #pragma unroll
        for (int it = 0; it < 2; ++it) {
            int f = tid + 512 * it;
            int co = f >> 3, nn0 = (f & 7) * 4;
            size_t gidx = ((size_t)b * Cn + co) * Nn + n0 + sub * 32 + nn0;
            float4 xv = *(const float4*)&x[gidx];
            float scv = sc[co], bsv = bs[co];
            float4 o;
            float v0 = tl[sub*32+nn0+0] * sa_s[nn0+0][co] + sb_s[nn0+0][co];
            float v1 = tl[sub*32+nn0+1] * sa_s[nn0+1][co] + sb_s[nn0+1][co];
            float v2 = tl[sub*32+nn0+2] * sa_s[nn0+2][co] + sb_s[nn0+2][co];
            float v3 = tl[sub*32+nn0+3] * sa_s[nn0+3][co] + sb_s[nn0+3][co];
            o.x = v0 * scv + bsv + xv.x;
            o.y = v1 * scv + bsv + xv.y;
            o.z = v2 * scv + bsv + xv.z;
            o.w = v3 * scv + bsv + xv.w;
            *(float4*)&out[gidx] = o;
        }
        __syncthreads();
        #pragma unroll
        for (int i2 = 0; i2 < 8; ++i2) pf[i2] = pf2[i2];
    }
}

// ---------------------------------------------------------------------------
extern "C" void kernel_launch(void* const* d_in, const int* in_sizes, int n_in,
                              void* d_out, int out_size, void* d_ws, size_t ws_size,
                              hipStream_t stream)
{
    const float* x  = (const float*)d_in[0];
    const float* w1 = (const float*)d_in[1];
    const float* b1 = (const float*)d_in[2];
    const float* w3 = (const float*)d_in[3];
    const float* b3 = (const float*)d_in[4];
    const float* w4 = (const float*)d_in[5];
    const float* b4 = (const float*)d_in[6];
    const float* w5 = (const float*)d_in[7];
    const float* w2 = (const float*)d_in[8];
    const float* b2 = (const float*)d_in[9];
    const float* gm = (const float*)d_in[10];
    const float* bt = (const float*)d_in[11];
    const float* mn = (const float*)d_in[12];
    const float* vr = (const float*)d_in[13];
    float* out = (float*)d_out;

    float* ws = (float*)d_ws;
    const size_t FTOT = 3823872;           // floats (~15.3 MB)
    if (ws_size < FTOT * sizeof(float)) return;

    float*  t_w  = ws;                      // 32768
    float*  p_w  = ws + 32768;              // 8192
    float*  ps_w = ws + 40960;              // 8192
    int*    pm_w = (int*)(ws + 49152);      // 8192
    float*  g_w  = ws + 581632;             // 1048576
    float2* csab = (float2*)(ws + 1630208); // 8192 float2 = 65536 fl
    float2* SAB  = (float2*)(ws + 1695744); // 1025*128*8 fl2 = 2099200 fl

    k_conv <<<dim3(64, 8), 256, 0, stream>>>(x, w1, b1, w3, b3, w4, b4, w5, w2,
                                             t_w, p_w, g_w);
    k_rank <<<dim3(32, 8), 512, 0, stream>>>(p_w, ps_w, pm_w);
    k_scanA<<<dim3(32, 8), 512, 0, stream>>>(g_w, ps_w, pm_w, csab);
    k_scanC<<<dim3(32, 8), 512, 0, stream>>>(g_w, ps_w, pm_w, csab, SAB);
    k_final<<<dim3(32, 8), 512, 0, stream>>>(x, t_w, ps_w, SAB, b2, gm, bt, mn, vr, out);
}